// Round 3
// baseline (159.885 us; speedup 1.0000x reference)
//
#include <hip/hip_runtime.h>
#include <math.h>

#define N_IN   512
#define N_OUT  256
#define NCOEF  257
#define BATCH  1024
#define LN_EPS 1e-5f

#define OC 16        // o per block
#define IG 32        // i per block
#define BC 256       // b per block

#define G0F (-1.0f - 3.0f * (2.0f / 254.0f))

// slab layout: element (c, oo) at slab[c*16 + (oo ^ (((c>>4)&3)<<2))]
// read of (row p, cols og*4..+3) is one aligned ds_read_b128.

static __device__ __forceinline__ unsigned pk_bf16x2(float a, float b) {
    unsigned ua = ((__float_as_uint(a) + 0x8000u) >> 16) & 0xffffu;
    unsigned ub = (__float_as_uint(b) + 0x8000u) & 0xffff0000u;
    return ua | ub;
}

__global__ __launch_bounds__(256, 4) void kan_main(
    const float* __restrict__ x, const float* __restrict__ W,
    const float* __restrict__ sw, float* __restrict__ part)
{
    const int bid = blockIdx.x;
    const int oc = bid & 15;
    const int ig = (bid >> 4) & 15;
    const int bc = bid >> 8;
    const int o0 = oc * OC, i0 = ig * IG, b0 = bc * BC;
    const int t = threadIdx.x;

    __shared__ __align__(16) float slab[NCOEF * 16];  // 16.45 KB
    __shared__ __align__(16) uint4 wpk[BC];           // 4 KB
    __shared__ __align__(16) float Wl[OC];

    // compute mapping
    const int wv = t >> 6, bl = (t >> 2) & 15, og = t & 3;
    // staging mapping
    const int soo = t >> 4, scb = t & 15;
    const int colp = soo ^ (((scb >> 2) & 3) << 2);

    const float* rp  = sw + ((size_t)(o0 + soo) * N_IN + i0) * NCOEF;
    const float* xp  = x + (size_t)(b0 + t) * N_IN + i0;
    const float* wgp = W + (size_t)(o0 + (t & 15)) * N_IN + i0;

    // ---- prologue prefetch (ii = 0)
    float pf[16], pfT, xcur, Wcur;
#pragma unroll
    for (int e = 0; e < 4; ++e) {
        const int c0 = e * 64 + scb * 4;
        pf[e * 4 + 0] = rp[c0 + 0]; pf[e * 4 + 1] = rp[c0 + 1];
        pf[e * 4 + 2] = rp[c0 + 2]; pf[e * 4 + 3] = rp[c0 + 3];
    }
    pfT  = (scb == 15) ? rp[256] : 0.f;
    xcur = xp[0];
    Wcur = (t < OC) ? wgp[0] : 0.f;

    float4 acc[4];
#pragma unroll
    for (int bp = 0; bp < 4; ++bp) acc[bp] = make_float4(0.f, 0.f, 0.f, 0.f);

    for (int ii = 0; ii < IG; ++ii) {
        // ---- per-(b,i) weight pack from xcur (VALU only, pre-barrier)
        uint4 wp;
        {
            const float xv = xcur;
            const float e2 = __expf(2.f * xv);
            const float tx = 1.f - 2.f / (e2 + 1.f);   // tanh
            const float u  = (xv - G0F) * 127.f;
            const bool has = (u >= 0.f) && (u < 260.f);
            const float uf = has ? u : 0.f;
            int m = (int)uf;
            if (m > 259) m = 259;
            const float tt = uf - (float)m;
            const float t2 = tt * tt, t3 = t2 * tt;
            const float omt = 1.f - tt;
            float a0 = omt * omt * omt * (1.f / 6.f);
            float a1 = (3.f * t3 - 6.f * t2 + 4.f) * (1.f / 6.f);
            float a2 = (-3.f * t3 + 3.f * t2 + 3.f * tt + 1.f) * (1.f / 6.f);
            float a3 = t3 * (1.f / 6.f);
            if (!has) { a0 = a1 = a2 = a3 = 0.f; }
            const int pb  = m - 3;
            const int pbc = pb < 0 ? 0 : (pb > 253 ? 253 : pb);
            const int d   = pbc - pb;   // in [-3,3]
            if (d >= 1)  { a0 = a1; a1 = a2; a2 = a3; a3 = 0.f; }
            if (d >= 2)  { a0 = a1; a1 = a2; a2 = a3; a3 = 0.f; }
            if (d >= 3)  { a0 = a1; a1 = a2; a2 = a3; a3 = 0.f; }
            if (d <= -1) { a3 = a2; a2 = a1; a1 = a0; a0 = 0.f; }
            if (d <= -2) { a3 = a2; a2 = a1; a1 = a0; a0 = 0.f; }
            if (d <= -3) { a3 = a2; a2 = a1; a1 = a0; a0 = 0.f; }
            wp.x = pk_bf16x2(a0, a1);
            wp.y = pk_bf16x2(a2, a3);
            wp.z = __float_as_uint(tx);
            wp.w = (unsigned)pbc;
        }

        __syncthreads();   // previous iteration's readers done

        // ---- staged regs -> LDS
#pragma unroll
        for (int e = 0; e < 4; ++e) {
            const int c0 = e * 64 + scb * 4;
            float* wpt = &slab[(c0 << 4) + colp];
            wpt[0]  = pf[e * 4 + 0];
            wpt[16] = pf[e * 4 + 1];
            wpt[32] = pf[e * 4 + 2];
            wpt[48] = pf[e * 4 + 3];
        }
        if (scb == 15) slab[(256 << 4) + soo] = pfT;
        wpk[t] = wp;
        if (t < OC) Wl[t] = Wcur;
        __syncthreads();

        // ---- issue prefetch for ii+1 (completes under compute)
        if (ii + 1 < IG) {
            rp += NCOEF;
#pragma unroll
            for (int e = 0; e < 4; ++e) {
                const int c0 = e * 64 + scb * 4;
                pf[e * 4 + 0] = rp[c0 + 0]; pf[e * 4 + 1] = rp[c0 + 1];
                pf[e * 4 + 2] = rp[c0 + 2]; pf[e * 4 + 3] = rp[c0 + 3];
            }
            pfT  = (scb == 15) ? rp[256] : 0.f;
            xcur = xp[ii + 1];
            if (t < OC) Wcur = wgp[ii + 1];
        }

        // ---- compute
        const float4 Wv = *reinterpret_cast<const float4*>(&Wl[og << 2]);
#pragma unroll
        for (int bp = 0; bp < 4; ++bp) {
            const int lb = wv * 64 + bp * 16 + bl;
            const uint4 u = wpk[lb];          // one b128, broadcast x4
            const float tx = __uint_as_float(u.z);
            float4 a = acc[bp];
            a.x += tx * Wv.x; a.y += tx * Wv.y;
            a.z += tx * Wv.z; a.w += tx * Wv.w;
            if (u.x | u.y) {                  // ~69% of lanes: spline support
                const int pb = (int)u.w;
                const float w0 = __uint_as_float(u.x << 16);
                const float w1 = __uint_as_float(u.x & 0xffff0000u);
                const float w2 = __uint_as_float(u.y << 16);
                const float w3 = __uint_as_float(u.y & 0xffff0000u);
#pragma unroll
                for (int k = 0; k < 4; ++k) {
                    const int p = pb + k;
                    const int cidx = (p << 4) + ((og ^ ((p >> 4) & 3)) << 2);
                    const float4 s4 = *reinterpret_cast<const float4*>(&slab[cidx]);
                    const float wk = (k == 0) ? w0 : (k == 1) ? w1
                                   : (k == 2) ? w2 : w3;
                    a.x += wk * s4.x; a.y += wk * s4.y;
                    a.z += wk * s4.z; a.w += wk * s4.w;
                }
            }
            acc[bp] = a;
        }
    }

    // ---- write partial slab [ig][b][o]
    float* dst = part + ((size_t)ig * BATCH + b0) * N_OUT + o0 + (og << 2);
#pragma unroll
    for (int bp = 0; bp < 4; ++bp) {
        const int lb = wv * 64 + bp * 16 + bl;
        *reinterpret_cast<float4*>(&dst[(size_t)lb * N_OUT]) = acc[bp];
    }
}

__global__ __launch_bounds__(256) void kan_ln(
    const float* __restrict__ part, const float* __restrict__ prelu_a,
    float* __restrict__ out)
{
    const int b = blockIdx.x;
    const int t = threadIdx.x;

    float s = 0.f;
#pragma unroll
    for (int k = 0; k < 16; ++k)
        s += part[((size_t)k * BATCH + b) * N_OUT + t];

    float v1 = s, v2 = s * s;
#pragma unroll
    for (int d = 1; d < 64; d <<= 1) {
        v1 += __shfl_xor(v1, d);
        v2 += __shfl_xor(v2, d);
    }
    __shared__ float r1[4], r2[4];
    if ((t & 63) == 0) { r1[t >> 6] = v1; r2[t >> 6] = v2; }
    __syncthreads();
    const float tot1 = r1[0] + r1[1] + r1[2] + r1[3];
    const float tot2 = r2[0] + r2[1] + r2[2] + r2[3];

    const float mu  = tot1 * (1.f / N_OUT);
    const float var = tot2 * (1.f / N_OUT) - mu * mu;
    const float inv = rsqrtf(var + LN_EPS);
    const float yn  = (s - mu) * inv;
    const float a   = prelu_a[0];
    out[(size_t)b * N_OUT + t] = (yn >= 0.f) ? yn : a * yn;
}

extern "C" void kernel_launch(void* const* d_in, const int* in_sizes, int n_in,
                              void* d_out, int out_size, void* d_ws, size_t ws_size,
                              hipStream_t stream)
{
    const float* x  = (const float*)d_in[0];
    const float* W  = (const float*)d_in[1];
    const float* sw = (const float*)d_in[2];
    const float* pa = (const float*)d_in[3];
    float* out  = (float*)d_out;
    float* part = (float*)d_ws;   // 16 * 1024 * 256 floats = 16 MB

    kan_main<<<dim3(1024), 256, 0, stream>>>(x, W, sw, part);
    kan_ln<<<dim3(1024), 256, 0, stream>>>(part, pa, out);
}

// Round 4
// 117.127 us; speedup vs baseline: 1.3651x; 1.3651x over previous
//
#include <hip/hip_runtime.h>
#include <math.h>

#define N_IN   512
#define N_OUT  256
#define NCOEF  257
#define BATCH  1024
#define LN_EPS 1e-5f
#define G0F (-1.0f - 3.0f * (2.0f / 254.0f))

// ---- bf16 pack helpers ----
static __device__ __forceinline__ unsigned pk_bf16x2(float a, float b) {
    unsigned ua = ((__float_as_uint(a) + 0x8000u) >> 16) & 0xffffu;
    unsigned ub = (__float_as_uint(b) + 0x8000u) & 0xffff0000u;
    return ua | ub;
}

// per-(b,i) spline weights + tanh, packed into uint4 (validated rounds 2-3)
static __device__ __forceinline__ uint4 spline_pack(float xv) {
    const float e2 = __expf(2.f * xv);
    const float tx = 1.f - 2.f / (e2 + 1.f);        // tanh(xv)
    const float u  = (xv - G0F) * 127.f;
    const bool has = (u >= 0.f) && (u < 260.f);
    const float uf = has ? u : 0.f;
    int m = (int)uf;
    if (m > 259) m = 259;
    const float tt = uf - (float)m;
    const float t2 = tt * tt, t3 = t2 * tt;
    const float omt = 1.f - tt;
    float a0 = omt * omt * omt * (1.f / 6.f);
    float a1 = (3.f * t3 - 6.f * t2 + 4.f) * (1.f / 6.f);
    float a2 = (-3.f * t3 + 3.f * t2 + 3.f * tt + 1.f) * (1.f / 6.f);
    float a3 = t3 * (1.f / 6.f);
    if (!has) { a0 = a1 = a2 = a3 = 0.f; }
    const int pb  = m - 3;
    const int pbc = pb < 0 ? 0 : (pb > 253 ? 253 : pb);
    const int d   = pbc - pb;                       // [-3,3]
    if (d >= 1)  { a0 = a1; a1 = a2; a2 = a3; a3 = 0.f; }
    if (d >= 2)  { a0 = a1; a1 = a2; a2 = a3; a3 = 0.f; }
    if (d >= 3)  { a0 = a1; a1 = a2; a2 = a3; a3 = 0.f; }
    if (d <= -1) { a3 = a2; a2 = a1; a1 = a0; a0 = 0.f; }
    if (d <= -2) { a3 = a2; a2 = a1; a1 = a0; a0 = 0.f; }
    if (d <= -3) { a3 = a2; a2 = a1; a1 = a0; a0 = 0.f; }
    uint4 r;
    r.x = pk_bf16x2(a0, a1);
    r.y = pk_bf16x2(a2, a3);
    r.z = __float_as_uint(tx);
    r.w = (unsigned)pbc;
    return r;
}

// slab: [buf][sub][row c (257) x 8 dwords]; dword d holds bf16 cols (2d, 2d+1),
// stored at d' = d ^ ((((c>>4)&3))<<1)  (b64-pair-preserving XOR swizzle)
__global__ __launch_bounds__(512, 4) void kan_main(
    const float* __restrict__ x, const float* __restrict__ W,
    const float* __restrict__ sw, float* __restrict__ part)
{
    const int bid = blockIdx.x;
    const int bc = bid & 1;             // fastest: slab-sharers co-resident
    const int oc = (bid >> 1) & 15;
    const int ig = bid >> 5;
    const int o0 = oc * 16, i0 = ig * 32, b0 = bc * 512;
    const int t = threadIdx.x;

    __shared__ __align__(16) unsigned slab[2][2][NCOEF * 8];  // 32.9 KB
    __shared__ __align__(16) uint4 wpk[2][512];               // 16 KB, wave-private
    __shared__ __align__(16) float Wl[2][2][16];

    // compute mapping: wave wv owns b = b0 + wv*64 + (bp*16 + bl)
    const int wv = t >> 6, bl = (t >> 2) & 15, og = t & 3;
    // staging mapping: half-block stages sub-slab `half`; 8 col-pairs x 32 c-threads
    const int half = t >> 8;
    const int s    = (t & 255) >> 5;     // dword-col (covers float cols 2s,2s+1)
    const int scb  = t & 31;             // c-group
    const int sp   = s ^ (((scb >> 2) & 3) << 1);   // swizzled dword-col
    // W staging (t<32): sub = t>>4, oo = t&15
    const int wsub = t >> 4, woo = t & 15;

    const float* rpA = sw + ((size_t)(o0 + 2 * s) * N_IN + i0 + half) * NCOEF;
    const float* rpB = rpA + (size_t)N_IN * NCOEF;
    const float* xptr = x + (size_t)(b0 + t) * N_IN + i0;
    const float* wptr = W + (size_t)(o0 + woo) * N_IN + i0 + wsub;

    float4 pfA[2], pfB[2];
    float tTa = 0.f, tTb = 0.f, Wc = 0.f;
    float2 xc;

#define LDPAIR(pi) do {                                                   \
        const float* _a = rpA + (size_t)(pi) * (2 * NCOEF);               \
        const float* _b = rpB + (size_t)(pi) * (2 * NCOEF);               \
        pfA[0] = *(const float4*)&_a[scb * 4];                            \
        pfA[1] = *(const float4*)&_a[128 + scb * 4];                      \
        pfB[0] = *(const float4*)&_b[scb * 4];                            \
        pfB[1] = *(const float4*)&_b[128 + scb * 4];                      \
        if (scb == 31) { tTa = _a[256]; tTb = _b[256]; }                  \
    } while (0)

#define STAGE(wb) do {                                                    \
        unsigned* _sl = &slab[wb][half][0];                               \
        _Pragma("unroll")                                                 \
        for (int _e = 0; _e < 2; ++_e) {                                  \
            const int _c0 = _e * 128 + scb * 4;                           \
            const float4 _va = pfA[_e], _vb = pfB[_e];                    \
            const int _ba = _c0 * 8 + sp;                                 \
            _sl[_ba]      = pk_bf16x2(_va.x, _vb.x);                      \
            _sl[_ba + 8]  = pk_bf16x2(_va.y, _vb.y);                      \
            _sl[_ba + 16] = pk_bf16x2(_va.z, _vb.z);                      \
            _sl[_ba + 24] = pk_bf16x2(_va.w, _vb.w);                      \
        }                                                                 \
        if (scb == 31) _sl[256 * 8 + s] = pk_bf16x2(tTa, tTb);            \
    } while (0)

    // ---- prologue: stage pair 0 into buf 0; prefetch pair 1
    LDPAIR(0);
    xc = *(const float2*)&xptr[0];
    if (t < 32) Wc = wptr[0];
    STAGE(0);
    if (t < 32) Wl[0][wsub][woo] = Wc;
    LDPAIR(1);
    if (t < 32) Wc = wptr[2];

    float4 acc[4];
#pragma unroll
    for (int bp = 0; bp < 4; ++bp) acc[bp] = make_float4(0.f, 0.f, 0.f, 0.f);

    __syncthreads();

    for (int n = 0; n < 16; ++n) {
        const int buf = n & 1;

        // wpk for pair n (wave-private LDS: no barrier interplay needed)
        wpk[0][t] = spline_pack(xc.x);
        wpk[1][t] = spline_pack(xc.y);
        if (n + 1 < 16) xc = *(const float2*)&xptr[2 * (n + 1)];

        __syncthreads();   // dbuf barrier

        if (n + 1 < 16) {
            STAGE(buf ^ 1);
            if (t < 32) Wl[buf ^ 1][wsub][woo] = Wc;
            if (n + 2 < 16) {
                LDPAIR(n + 2);
                if (t < 32) Wc = wptr[2 * (n + 2)];
            }
        }

        // ---- compute pair n
#pragma unroll
        for (int sub = 0; sub < 2; ++sub) {
            const float4 Wv = *(const float4*)&Wl[buf][sub][og << 2];
            const unsigned* sl = &slab[buf][sub][0];
#pragma unroll
            for (int bp = 0; bp < 4; ++bp) {
                const uint4 u = wpk[sub][wv * 64 + (bp << 4) + bl];
                const float tx = __uint_as_float(u.z);
                float4 a = acc[bp];
                a.x += tx * Wv.x; a.y += tx * Wv.y;
                a.z += tx * Wv.z; a.w += tx * Wv.w;
                if (u.x | u.y) {
                    const float w0 = __uint_as_float(u.x << 16);
                    const float w1 = __uint_as_float(u.x & 0xffff0000u);
                    const float w2 = __uint_as_float(u.y << 16);
                    const float w3 = __uint_as_float(u.y & 0xffff0000u);
                    const int pb = (int)u.w;
#pragma unroll
                    for (int k = 0; k < 4; ++k) {
                        const int p = pb + k;
                        const int dd = (p << 3) + ((og ^ ((p >> 4) & 3)) << 1);
                        const uint2 sv = *(const uint2*)&sl[dd];
                        const float wk = (k == 0) ? w0 : (k == 1) ? w1
                                       : (k == 2) ? w2 : w3;
                        a.x += wk * __uint_as_float(sv.x << 16);
                        a.y += wk * __uint_as_float(sv.x & 0xffff0000u);
                        a.z += wk * __uint_as_float(sv.y << 16);
                        a.w += wk * __uint_as_float(sv.y & 0xffff0000u);
                    }
                }
                acc[bp] = a;
            }
        }
    }

    // ---- write partial slab [ig][b][o]
    float* dst = part + ((size_t)ig * BATCH + b0) * N_OUT + o0 + (og << 2);
#pragma unroll
    for (int bp = 0; bp < 4; ++bp) {
        const int lb = wv * 64 + (bp << 4) + bl;
        *reinterpret_cast<float4*>(&dst[(size_t)lb * N_OUT]) = acc[bp];
    }
#undef LDPAIR
#undef STAGE
}

__global__ __launch_bounds__(256) void kan_ln(
    const float* __restrict__ part, const float* __restrict__ prelu_a,
    float* __restrict__ out)
{
    const int b = blockIdx.x;
    const int t = threadIdx.x;

    float sv = 0.f;
#pragma unroll
    for (int k = 0; k < 16; ++k)
        sv += part[((size_t)k * BATCH + b) * N_OUT + t];

    float v1 = sv, v2 = sv * sv;
#pragma unroll
    for (int d = 1; d < 64; d <<= 1) {
        v1 += __shfl_xor(v1, d);
        v2 += __shfl_xor(v2, d);
    }
    __shared__ float r1[4], r2[4];
    if ((t & 63) == 0) { r1[t >> 6] = v1; r2[t >> 6] = v2; }
    __syncthreads();
    const float tot1 = r1[0] + r1[1] + r1[2] + r1[3];
    const float tot2 = r2[0] + r2[1] + r2[2] + r2[3];

    const float mu  = tot1 * (1.f / N_OUT);
    const float var = tot2 * (1.f / N_OUT) - mu * mu;
    const float inv = rsqrtf(var + LN_EPS);
    const float yn  = (sv - mu) * inv;
    const float a   = prelu_a[0];
    out[(size_t)b * N_OUT + t] = (yn >= 0.f) ? yn : a * yn;
}

extern "C" void kernel_launch(void* const* d_in, const int* in_sizes, int n_in,
                              void* d_out, int out_size, void* d_ws, size_t ws_size,
                              hipStream_t stream)
{
    const float* x  = (const float*)d_in[0];
    const float* W  = (const float*)d_in[1];
    const float* sw = (const float*)d_in[2];
    const float* pa = (const float*)d_in[3];
    float* out  = (float*)d_out;
    float* part = (float*)d_ws;   // 16 * 1024 * 256 floats = 16 MB

    kan_main<<<dim3(512), 512, 0, stream>>>(x, W, sw, part);
    kan_ln<<<dim3(1024), 256, 0, stream>>>(part, pa, out);
}